// Round 5
// baseline (118.163 us; speedup 1.0000x reference)
//
#include <hip/hip_runtime.h>
#include <hip/hip_bf16.h>

typedef _Float16 f16;
typedef _Float16 f16x8 __attribute__((ext_vector_type(8)));
typedef float f32x4 __attribute__((ext_vector_type(4)));

constexpr int TS = 2048;   // time steps / params length
constexpr int BB = 4096;   // batch rows

// chunk-index XOR swizzle: spreads stride-32-float window reads across bank
// groups (16-way conflict -> conflict-free). Bijective on any 64-chunk line.
__device__ __forceinline__ int swz4(int c) { return c ^ ((c >> 3) & 7); }

struct ToepShared { char Xs[16384]; char Ws[8192]; };

union MegaShared {
  ToepShared t;
  struct {  // h-block state (28.7 KB)
    float rp1[2048];   // swizzled: rp1[y] = p[2046-y] (y<=2046), else 0
    float h[2048];     // linear impulse response
    float hist[1024];  // linear
    float hbuf[2052];  // swizzled padded hist window
  } hb;
};

// ---------------------------------------------------------------------------
// toep body: triangular Toeplitz x dense GEMM via mfma_f32_16x16x32_f16.
//   REV=true  (stage A): u[b,m] = bias + sum_{k>=m} prv[k-m] * x[b,k] -> f16
//   REV=false (stage C): y[b,m] =        sum_{k<=m} h[m-k]  * u[b,k] -> f32
// Block: 128 rows x 64 cols, 4 waves (2x2), BK=64, column pairing (px,31-px).
// ---------------------------------------------------------------------------
template <bool REV>
__device__ void toep_body(ToepShared& lds, int w, const f16* __restrict__ Xg,
                          const char* __restrict__ Wg,
                          const float* __restrict__ biasp, void* __restrict__ Yg) {
  char* Xs = lds.Xs;
  char* Ws = lds.Ws;
  const int tid = threadIdx.x;
  const int lane = tid & 63;
  const int wid = tid >> 6;
  const int wrow = (wid >> 1) * 64;
  const int wcol = (wid & 1) * 32;
  const int px = w & 15;
  const int b0 = (w >> 4) * 128;

  float binit = 0.0f;
  if (REV) binit = biasp[0];

  for (int phase = 0; phase < 2; ++phase) {
    const int mblk = phase ? (31 - px) : px;
    const int m0 = mblk * 64;
    const int k0b = REV ? m0 : 0;
    const int k0e = REV ? TS : (m0 + 64);

    f32x4 acc[4][2];
    #pragma unroll
    for (int i = 0; i < 4; ++i)
      #pragma unroll
      for (int j = 0; j < 2; ++j) acc[i][j] = {binit, binit, binit, binit};

    for (int k0 = k0b; k0 < k0e; k0 += 64) {
      __syncthreads();
      // stage X tile: 16 x 1KB, inverse-swizzled per-lane global source
      #pragma unroll
      for (int t2 = 0; t2 < 4; ++t2) {
        const int t = wid * 4 + t2;
        const int row = t * 8 + (lane >> 3);
        const char* src = (const char*)Xg + ((size_t)(b0 + row) * TS + k0) * 2
                          + (((lane & 7) * 16) ^ ((row & 7) << 4));
        __builtin_amdgcn_global_load_lds(
            (const __attribute__((address_space(1))) unsigned int*)src,
            (__attribute__((address_space(3))) unsigned int*)(Xs + t * 1024),
            16, 0, 0);
      }
      // stage W tile (pre-swizzled in global): 8 x 1KB
      const int dlt = (REV ? (k0 - m0) : (m0 - k0)) >> 6;
      const char* wsrc = Wg + (size_t)dlt * 8192;
      #pragma unroll
      for (int p = 0; p < 2; ++p) {
        const int t = wid * 2 + p;
        __builtin_amdgcn_global_load_lds(
            (const __attribute__((address_space(1))) unsigned int*)(wsrc + t * 1024 + lane * 16),
            (__attribute__((address_space(3))) unsigned int*)(Ws + t * 1024),
            16, 0, 0);
      }
      __syncthreads();

      #pragma unroll
      for (int ks = 0; ks < 2; ++ks) {
        const int colb = ks * 64 + ((lane >> 4) * 16);
        f16x8 af[4], bf[2];
        #pragma unroll
        for (int i = 0; i < 4; ++i) {
          const int row = wrow + i * 16 + (lane & 15);
          af[i] = *(const f16x8*)(Xs + row * 128 + (colb ^ ((row & 7) << 4)));
        }
        #pragma unroll
        for (int j = 0; j < 2; ++j) {
          const int n = wcol + j * 16 + (lane & 15);
          bf[j] = *(const f16x8*)(Ws + n * 128 + (colb ^ ((n & 7) << 4)));
        }
        #pragma unroll
        for (int i = 0; i < 4; ++i)
          #pragma unroll
          for (int j = 0; j < 2; ++j)
            acc[i][j] = __builtin_amdgcn_mfma_f32_16x16x32_f16(
                af[i], bf[j], acc[i][j], 0, 0, 0);
      }
    }

    // epilogue: C/D layout col=lane&15, row=(lane>>4)*4+r
    #pragma unroll
    for (int i = 0; i < 4; ++i) {
      #pragma unroll
      for (int j = 0; j < 2; ++j) {
        #pragma unroll
        for (int r = 0; r < 4; ++r) {
          const int row = b0 + wrow + i * 16 + (lane >> 4) * 4 + r;
          const int col = m0 + wcol + j * 16 + (lane & 15);
          if (REV)
            ((f16*)Yg)[(size_t)row * TS + col] = (f16)acc[i][j][r];
          else
            ((float*)Yg)[(size_t)row * TS + col] = acc[i][j][r];
        }
      }
    }
  }
}

// ---------------------------------------------------------------------------
// h-block (256 threads): impulse response by 6 doubling phases with 16x16
// register tiles (group-looped, gi += 32), then stage-C W tiles.
//   doubling n -> 2n:  hist[i] = sum_{m<n} h[m] p[n-1+i-m]      (i in [0,n))
//                      h[n+i]  = sum_{r<=i} h[r] hist[i-r]
// ---------------------------------------------------------------------------
__device__ void h_block_body(MegaShared& lds, const float* __restrict__ params,
                             char* __restrict__ WgC) {
  float* rp1 = lds.hb.rp1;
  float* h_s = lds.hb.h;
  float* hist = lds.hb.hist;
  float* hb = lds.hb.hbuf;

  const int tid = threadIdx.x;  // 0..255
  const int lane = tid & 63;
  const int wave = tid >> 6;

  for (int c = tid; c < 512; c += 256) {  // init rp1, 4-float chunk per iter
    const int y = c * 4;
    f32x4 v;
    v[0] = params[2046 - y];
    v[1] = params[2045 - y];
    v[2] = params[2044 - y];
    v[3] = (y + 3 < 2047) ? params[2043 - y] : 0.0f;
    *(f32x4*)&rp1[swz4(c) * 4] = v;
  }
  __syncthreads();

  // bootstrap h[0..31] in wave 0: h[m] = sum_{l<m} h[l] p[m-1-l]
  if (wave == 0) {
    float hv = (lane == 0) ? 1.0f : 0.0f;
    for (int m = 1; m < 32; ++m) {
      float partial = 0.0f;
      if (lane < m) {
        const int yi = 2047 - m + lane;  // p[m-1-lane]
        partial = hv * rp1[swz4(yi >> 2) * 4 + (yi & 3)];
      }
      #pragma unroll
      for (int off = 32; off; off >>= 1) partial += __shfl_xor(partial, off);
      if (lane == m) hv = partial;
    }
    if (lane < 32) h_s[lane] = hv;
  }
  __syncthreads();

  const int sub = tid & 7;
  const int g0 = tid >> 3;  // 0..31

  for (int n = 32; n < 2048; n <<= 1) {
    const int ng16 = n >> 4;
    const int T = (n >= 128) ? (n >> 7) : 1;

    // ---------- phase H: hist ----------
    for (int gi = g0; gi < ng16; gi += 32) {
      float acc[16];
      #pragma unroll
      for (int j = 0; j < 16; ++j) acc[j] = 0.0f;
      const int ybase = (2047 - n) - gi * 16 - 15;
      for (int t = 0; t < T; ++t) {
        const int m16 = (sub + 8 * t) * 16;
        if (m16 < n) {
          const int c0 = (ybase + m16) >> 2;
          f32x4 wv[8];
          #pragma unroll
          for (int q = 0; q < 8; ++q) wv[q] = *(const f32x4*)&rp1[swz4(c0 + q) * 4];
          f32x4 hv4[4];
          #pragma unroll
          for (int q = 0; q < 4; ++q) hv4[q] = *(const f32x4*)&h_s[m16 + 4 * q];
          #pragma unroll
          for (int d = 0; d < 16; ++d) {
            const float hd = hv4[d >> 2][d & 3];
            #pragma unroll
            for (int j = 0; j < 16; ++j) {
              const int k = d - j + 15;  // w[k] = p[n-1+i-m]
              acc[j] += hd * wv[k >> 2][k & 3];
            }
          }
        }
      }
      #pragma unroll
      for (int j = 0; j < 16; ++j) {
        acc[j] += __shfl_xor(acc[j], 1);
        acc[j] += __shfl_xor(acc[j], 2);
        acc[j] += __shfl_xor(acc[j], 4);
      }
      if (sub == 0) {
        #pragma unroll
        for (int q = 0; q < 4; ++q) {
          f32x4 v = {acc[4 * q], acc[4 * q + 1], acc[4 * q + 2], acc[4 * q + 3]};
          *(f32x4*)&hist[gi * 16 + 4 * q] = v;
        }
      }
    }
    __syncthreads();

    // ---------- padded window buffer hb[y] = hist[y-P], P = n+3 ----------
    const int P = n + 3;
    const int nchunk = (2 * n + 4) >> 2;
    for (int c = tid; c < nchunk; c += 256) {
      f32x4 v;
      #pragma unroll
      for (int q = 0; q < 4; ++q) {
        const int idx = 4 * c + q - P;
        v[q] = ((unsigned)idx < (unsigned)n) ? hist[idx] : 0.0f;
      }
      *(f32x4*)&hb[swz4(c) * 4] = v;
    }
    __syncthreads();

    // ---------- phase S: h[n+i] = sum_{r<=i} h[r] hist[i-r] ----------
    for (int gi = g0; gi < ng16; gi += 32) {
      float acc[16];
      #pragma unroll
      for (int j = 0; j < 16; ++j) acc[j] = 0.0f;
      int t_end = (gi >= sub) ? (((gi - sub) >> 3) + 1) : 0;
      if (t_end > T) t_end = T;
      const int ybase = P + gi * 16 - 15;
      for (int t = 0; t < t_end; ++t) {
        const int r16 = (sub + 8 * t) * 16;
        const int c0 = (ybase - r16) >> 2;
        f32x4 wv[8];
        #pragma unroll
        for (int q = 0; q < 8; ++q) wv[q] = *(const f32x4*)&hb[swz4(c0 + q) * 4];
        f32x4 hv4[4];
        #pragma unroll
        for (int q = 0; q < 4; ++q) hv4[q] = *(const f32x4*)&h_s[r16 + 4 * q];
        #pragma unroll
        for (int d = 0; d < 16; ++d) {
          const float hd = hv4[d >> 2][d & 3];
          #pragma unroll
          for (int j = 0; j < 16; ++j) {
            const int k = j - d + 15;  // hb pad gives 0 for r>i
            acc[j] += hd * wv[k >> 2][k & 3];
          }
        }
      }
      #pragma unroll
      for (int j = 0; j < 16; ++j) {
        acc[j] += __shfl_xor(acc[j], 1);
        acc[j] += __shfl_xor(acc[j], 2);
        acc[j] += __shfl_xor(acc[j], 4);
      }
      if (sub == 0) {
        #pragma unroll
        for (int q = 0; q < 4; ++q) {
          f32x4 v = {acc[4 * q], acc[4 * q + 1], acc[4 * q + 2], acc[4 * q + 3]};
          *(f32x4*)&h_s[n + gi * 16 + 4 * q] = v;
        }
      }
    }
    __syncthreads();
  }

  // ---- stage-C W tiles: W[k][n2] = h[dlt*64 + n2 - k], pre-swizzled ----
  const int n2 = tid >> 2, kq = tid & 3;
  for (int dlt = 0; dlt < 32; ++dlt) {
    char* tile = WgC + (size_t)dlt * 8192;
    #pragma unroll
    for (int part = 0; part < 2; ++part) {
      const int k8 = kq * 16 + part * 8;
      f16x8 v;
      #pragma unroll
      for (int ii = 0; ii < 8; ++ii) {
        const int k = k8 + ii;
        const int dd = dlt * 64 + n2 - k;
        v[ii] = ((unsigned)dd < (unsigned)TS) ? (f16)h_s[dd] : (f16)0.0f;
      }
      *(f16x8*)(tile + n2 * 128 + ((2 * k8) ^ ((n2 & 7) << 4))) = v;
    }
  }
}

// ---------------------------------------------------------------------------
// Kernel 1: convert X to f16 (blocks 0..2047) + build stage-A W tiles
// (blocks 2048..2079): W_A[k][n] = prv[dlt*64+k-n] = p[2047-(dlt*64+k-n)].
// ---------------------------------------------------------------------------
__global__ __launch_bounds__(256) void conv_prep(
    const float* __restrict__ X, f16* __restrict__ Xh,
    const float* __restrict__ params, char* __restrict__ Wg) {
  const int b = blockIdx.x;
  const int tid = threadIdx.x;
  if (b < 2048) {
    const size_t base = ((size_t)b * 256 + tid) * 16;
    const float4 a0 = *(const float4*)&X[base];
    const float4 a1 = *(const float4*)&X[base + 4];
    const float4 a2 = *(const float4*)&X[base + 8];
    const float4 a3 = *(const float4*)&X[base + 12];
    f16x8 v0 = {(f16)a0.x, (f16)a0.y, (f16)a0.z, (f16)a0.w,
                (f16)a1.x, (f16)a1.y, (f16)a1.z, (f16)a1.w};
    f16x8 v1 = {(f16)a2.x, (f16)a2.y, (f16)a2.z, (f16)a2.w,
                (f16)a3.x, (f16)a3.y, (f16)a3.z, (f16)a3.w};
    *(f16x8*)&Xh[base] = v0;
    *(f16x8*)&Xh[base + 8] = v1;
  } else {
    const int dlt = b - 2048;
    char* tile = Wg + (size_t)dlt * 8192;
    const int n = tid >> 2, kq = tid & 3;
    #pragma unroll
    for (int part = 0; part < 2; ++part) {
      const int k8 = kq * 16 + part * 8;
      f16x8 v;
      #pragma unroll
      for (int ii = 0; ii < 8; ++ii) {
        const int k = k8 + ii;
        const int dd = dlt * 64 + k - n;
        v[ii] = ((unsigned)dd < (unsigned)TS) ? (f16)params[2047 - dd] : (f16)0.0f;
      }
      *(f16x8*)(tile + n * 128 + ((2 * k8) ^ ((n & 7) << 4))) = v;
    }
  }
}

// ---------------------------------------------------------------------------
// Kernel 2: mega stage A. Blocks 0..511 = stage-A MFMA GEMM (XCD-swizzled);
// block 512 = h computation + stage-C W tiles (runs concurrently).
// ---------------------------------------------------------------------------
__global__ __launch_bounds__(256, 2) void mega_A(
    const f16* __restrict__ Xh, char* __restrict__ Wg,
    const float* __restrict__ biasp, f16* __restrict__ u,
    const float* __restrict__ params) {
  __shared__ MegaShared lds;
  const int b = blockIdx.x;
  if (b == 512) {
    h_block_body(lds, params, Wg + 32 * 8192);
    return;
  }
  toep_body<true>(lds.t, (b & 7) * 64 + (b >> 3), Xh, Wg, biasp, (void*)u);
}

// ---------------------------------------------------------------------------
// Kernel 3: stage C MFMA GEMM.
// ---------------------------------------------------------------------------
__global__ __launch_bounds__(256, 2) void toep_C(
    const f16* __restrict__ u, const char* __restrict__ WgC,
    float* __restrict__ out) {
  __shared__ ToepShared lds;
  const int b = blockIdx.x;
  toep_body<false>(lds, (b & 7) * 64 + (b >> 3), u, WgC, nullptr, (void*)out);
}

// ---------------------------------------------------------------------------
extern "C" void kernel_launch(void* const* d_in, const int* in_sizes, int n_in,
                              void* d_out, int out_size, void* d_ws, size_t ws_size,
                              hipStream_t stream) {
  const float* inputs = (const float*)d_in[0];  // [BB, TS] fp32
  const float* params = (const float*)d_in[1];  // [TS]
  const float* bias   = (const float*)d_in[2];  // [1]
  float* out = (float*)d_out;                   // [BB, TS] fp32

  char* ws = (char*)d_ws;
  f16*  Xh = (f16*)ws;                             // 16 MB
  f16*  u  = (f16*)(ws + (size_t)BB * TS * 2);     // 16 MB
  char* Wg = ws + (size_t)BB * TS * 4;             // 64 x 8 KB (A: 0..31, C: 32..63)

  conv_prep<<<2080, 256, 0, stream>>>(inputs, Xh, params, Wg);
  mega_A<<<513, 256, 0, stream>>>(Xh, Wg, bias, u, params);
  toep_C<<<512, 256, 0, stream>>>(u, Wg + 32 * 8192, out);
}